// Round 4
// baseline (346.913 us; speedup 1.0000x reference)
//
#include <hip/hip_runtime.h>
#include <hip/hip_bf16.h>

typedef __attribute__((ext_vector_type(8))) __bf16 bf16x8;
typedef __attribute__((ext_vector_type(4))) float f32x4;

#define DIM 1024
#define NHEADS 16
#define HDIM 64
#define BATCH 4
#define SEQ 2048
#define ROWS (BATCH * SEQ) /* 8192 */
#define SCL 0.18033688011112042f /* 0.125 * log2(e) */

__device__ inline unsigned short f2bf(float f) {
    __hip_bfloat16 h = __float2bfloat16(f);
    return *reinterpret_cast<unsigned short*>(&h);
}

// pack two floats to bf16x2 (RNE) -- v_cvt_pk_bf16_f32 on gfx950
__device__ inline unsigned int packbf2(float a, float b) {
    unsigned short ua = __builtin_bit_cast(unsigned short, (__bf16)a);
    unsigned short ub = __builtin_bit_cast(unsigned short, (__bf16)b);
    return (unsigned int)ua | ((unsigned int)ub << 16);
}

typedef const __attribute__((address_space(1))) unsigned int* gas_ptr;
typedef __attribute__((address_space(3))) unsigned int* las_ptr;
__device__ inline void gload16(const void* g, void* l) {
    __builtin_amdgcn_global_load_lds((gas_ptr)g, (las_ptr)l, 16, 0, 0);
}

// ---------------- cast fp32 -> bf16 (4 elems/thread) ----------------
__global__ __launch_bounds__(256) void cast_f32_bf16(const float* __restrict__ in,
                                                     unsigned short* __restrict__ out,
                                                     int n4) {
    int i = blockIdx.x * 256 + threadIdx.x;
    if (i < n4) {
        float4 v = ((const float4*)in)[i];
        ushort4 o;
        o.x = f2bf(v.x); o.y = f2bf(v.y); o.z = f2bf(v.z); o.w = f2bf(v.w);
        ((ushort4*)out)[i] = o;
    }
}

// ------------- transpose + cast: in[R][C] fp32 -> out[C][R] bf16 -------------
// rows with orow < srows get scaled by scl (folds softmax scale into W_qkv Q cols)
__global__ __launch_bounds__(256) void transpose_cast(const float* __restrict__ in,
                                                      unsigned short* __restrict__ out,
                                                      int R, int C, int srows, float scl) {
    __shared__ float tile[32][33];
    int c0 = blockIdx.x * 32, r0 = blockIdx.y * 32;
    int tx = threadIdx.x & 31, ty = threadIdx.x >> 5; // 32 x 8
#pragma unroll
    for (int i = 0; i < 32; i += 8) {
        int r = r0 + ty + i, c = c0 + tx;
        tile[ty + i][tx] = in[(size_t)r * C + c];
    }
    __syncthreads();
#pragma unroll
    for (int i = 0; i < 32; i += 8) {
        int orow = c0 + ty + i, oc = r0 + tx;
        float v = tile[tx][ty + i];
        if (orow < srows) v *= scl;
        out[(size_t)orow * R + oc] = f2bf(v);
    }
}

// ---------------- GEMM: C = A * Bt^T + bias ----------------
// bf16 path splits output: cols [0,1024) -> Cq [M][1024], cols [1024,N) -> Ckv [M][N-1024].
// qcols>0: bias for gn<qcols scaled by SCL. fp32 path: Cf [M][N].
__global__ __launch_bounds__(256) void gemm_bt_bias(const unsigned short* __restrict__ A,
                                                    const unsigned short* __restrict__ Bt,
                                                    const float* __restrict__ bias,
                                                    unsigned short* __restrict__ Cq,
                                                    unsigned short* __restrict__ Ckv,
                                                    float* __restrict__ Cf,
                                                    int M, int N, int K, int qcols) {
    __shared__ unsigned short As[128 * 32];
    __shared__ unsigned short Bs[128 * 32];
    const int tid = threadIdx.x;
    const int lane = tid & 63, wave = tid >> 6;
    const int wm = (wave >> 1) * 64, wn = (wave & 1) * 64;
    const int rowA = blockIdx.y * 128, rowB = blockIdx.x * 128;
    const int fr = lane & 15, fo = (lane >> 4) * 8;

    f32x4 acc[4][4] = {};

    for (int k0 = 0; k0 < K; k0 += 32) {
#pragma unroll
        for (int c = 0; c < 2; c++) {
            int o = c * 4096 + tid * 16; // byte offset in 8KB tile
            int r = o >> 6, cb = o & 63; // 64 B per row (32 bf16)
            int ldsb = c * 4096 + wave * 1024; // wave-uniform LDS base
            gload16((const char*)A + ((size_t)(rowA + r) * K + k0) * 2 + cb, (char*)As + ldsb);
            gload16((const char*)Bt + ((size_t)(rowB + r) * K + k0) * 2 + cb, (char*)Bs + ldsb);
        }
        __syncthreads();
        bf16x8 af[4], bfr[4];
#pragma unroll
        for (int i = 0; i < 4; i++) {
            af[i]  = *(const bf16x8*)(As + (wm + i * 16 + fr) * 32 + fo);
            bfr[i] = *(const bf16x8*)(Bs + (wn + i * 16 + fr) * 32 + fo);
        }
#pragma unroll
        for (int mi = 0; mi < 4; mi++)
#pragma unroll
            for (int ni = 0; ni < 4; ni++)
                acc[mi][ni] = __builtin_amdgcn_mfma_f32_16x16x32_bf16(af[mi], bfr[ni],
                                                                      acc[mi][ni], 0, 0, 0);
        __syncthreads();
    }

    // C/D layout: col = lane&15, row = (lane>>4)*4 + reg
    const int cn = lane & 15, cm = (lane >> 4) * 4;
    for (int ni = 0; ni < 4; ni++) {
        int gn = rowB + wn + ni * 16 + cn;
        float bv = bias[gn];
        if (gn < qcols) bv *= SCL;
        for (int mi = 0; mi < 4; mi++) {
#pragma unroll
            for (int r = 0; r < 4; r++) {
                int gm = rowA + wm + mi * 16 + cm + r;
                float v = acc[mi][ni][r] + bv;
                if (Cf) Cf[(size_t)gm * N + gn] = v;
                else if (gn < 1024) Cq[(size_t)gm * 1024 + gn] = f2bf(v);
                else Ckv[(size_t)gm * 2048 + (gn - 1024)] = f2bf(v);
            }
        }
    }
}

// -------- pack K,V into MFMA-fragment-major layouts --------
// Kp[bh][S/16][kc=2][lane=64][8]  (A-frag for S^T = K Q^T)
// Vp[bh][S/32][dt=4][lane=64][8]  (B-frag for O = P V)
__global__ __launch_bounds__(256) void pack_kv(const unsigned short* __restrict__ KVb, // [8192][2048]
                                               unsigned short* __restrict__ Kp,
                                               unsigned short* __restrict__ Vp) {
    __shared__ unsigned short Kt[64][72];
    __shared__ unsigned short Vt[64][68];
    const int tid = threadIdx.x;
    const int s0 = blockIdx.x * 64;
    const int by = blockIdx.y;
    const int b = by >> 4, h = by & 15;
    const size_t rowbase = ((size_t)(b * SEQ + s0)) * 2048 + h * 64;
    const int c = (tid & 7) * 8, rr = tid >> 3; // 8 x 32
#pragma unroll
    for (int p = 0; p < 2; p++) {
        int row = p * 32 + rr;
        const unsigned short* src = KVb + rowbase + (size_t)row * 2048;
        uint4 kv = *(const uint4*)(src + c);
        uint4 vv = *(const uint4*)(src + 1024 + c);
        *(uint2*)&Kt[row][c]     = make_uint2(kv.x, kv.y);
        *(uint2*)&Kt[row][c + 4] = make_uint2(kv.z, kv.w);
        *(uint2*)&Vt[row][c]     = make_uint2(vv.x, vv.y);
        *(uint2*)&Vt[row][c + 4] = make_uint2(vv.z, vv.w);
    }
    __syncthreads();
    // K fragments: 512 of them (kt[4] x kc[2] x lane[64]), 2 per thread
#pragma unroll
    for (int half = 0; half < 2; half++) {
        int f = half * 256 + tid;
        int kt = f >> 7, kc = (f >> 6) & 1, ln = f & 63;
        int lfr = ln & 15, lg = ln >> 4;
        uint4 d = *(const uint4*)&Kt[kt * 16 + lfr][kc * 32 + lg * 8];
        *(uint4*)(Kp + ((((size_t)by * 128) + (s0 >> 4) + kt) * 2 + kc) * 512 + ln * 8) = d;
    }
    // V fragments: 512 (kci[2] x dt[4] x lane[64]), 2 per thread
#pragma unroll
    for (int half = 0; half < 2; half++) {
        int f = half * 256 + tid;
        int kci = f >> 8, dt = (f >> 6) & 3, ln = f & 63;
        int lfr = ln & 15, lg = ln >> 4;
        unsigned short tmp[8];
#pragma unroll
        for (int j = 0; j < 8; j++) tmp[j] = Vt[kci * 32 + lg * 8 + j][dt * 16 + lfr];
        *(uint4*)(Vp + (((size_t)by * 64 + (s0 >> 5) + kci) * 4 + dt) * 512 + ln * 8) =
            *(uint4*)tmp;
    }
}

// ---------------- flash attention v4 ----------------
// K/V fragments read directly from global (L2) in packed layout; no barriers.
// 32 q/wave, 128 q/block. l via mfma(P, ones). P round-trip through per-wave LDS.
__global__ __launch_bounds__(256) void attn_kernel(const unsigned short* __restrict__ Qb, // [8192][1024] prescaled
                                                   const unsigned short* __restrict__ Kp,
                                                   const unsigned short* __restrict__ Vp,
                                                   unsigned short* __restrict__ attnb) { // [8192][1024]
    __shared__ unsigned short Ps[4][2][2048]; // [wave][qs][16 q][128 key] swizzled
    const int tid = threadIdx.x;
    const int lane = tid & 63, wave = tid >> 6;
    const int fr = lane & 15, g = lane >> 4, fo = g * 8, frl = fr & 7;
    const int by = blockIdx.y;
    const int b = by >> 4, h = by & 15;
    const int bS = b * SEQ, hcol = h * HDIM;
    const int q0 = blockIdx.x * 128 + wave * 32;

    bf16x8 qf[2][2];
#pragma unroll
    for (int qs = 0; qs < 2; qs++)
#pragma unroll
        for (int kc = 0; kc < 2; kc++)
            qf[qs][kc] = *(const bf16x8*)(Qb + (size_t)(bS + q0 + qs * 16 + fr) * 1024 +
                                          hcol + kc * 32 + fo);

    const __bf16 one = (__bf16)1.0f;
    const bf16x8 ones = {one, one, one, one, one, one, one, one};

    f32x4 oacc[2][4] = {};
    f32x4 lsum[2] = {};

    const unsigned short* kbase = Kp + (size_t)by * 128 * 1024 + lane * 8;
    const unsigned short* vbase = Vp + (size_t)by * 64 * 2048 + lane * 8;

    for (int kv0 = 0; kv0 < SEQ; kv0 += 128) {
        // scores + exp + P write (fused per kt to keep VGPR low)
#pragma unroll
        for (int kt = 0; kt < 8; kt++) {
            const unsigned short* kp = kbase + ((size_t)(kv0 >> 4) + kt) * 1024;
            bf16x8 kf0 = *(const bf16x8*)(kp);
            bf16x8 kf1 = *(const bf16x8*)(kp + 512);
            int cc = (kt * 2 + (g >> 1)) ^ frl;
#pragma unroll
            for (int qs = 0; qs < 2; qs++) {
                f32x4 a = {};
                a = __builtin_amdgcn_mfma_f32_16x16x32_bf16(kf0, qf[qs][0], a, 0, 0, 0);
                a = __builtin_amdgcn_mfma_f32_16x16x32_bf16(kf1, qf[qs][1], a, 0, 0, 0);
                uint2 pk;
                pk.x = packbf2(__builtin_amdgcn_exp2f(a[0]), __builtin_amdgcn_exp2f(a[1]));
                pk.y = packbf2(__builtin_amdgcn_exp2f(a[2]), __builtin_amdgcn_exp2f(a[3]));
                *(uint2*)(&Ps[wave][qs][fr * 128 + cc * 8 + (g & 1) * 4]) = pk;
            }
        }
        asm volatile("s_waitcnt lgkmcnt(0)" ::: "memory"); // P stores -> same-wave frag reads

        // O += P V ; l += P * ones
#pragma unroll
        for (int kc = 0; kc < 4; kc++) {
            int cc = (kc * 4 + g) ^ frl;
            bf16x8 pf0 = *(const bf16x8*)(&Ps[wave][0][fr * 128 + cc * 8]);
            bf16x8 pf1 = *(const bf16x8*)(&Ps[wave][1][fr * 128 + cc * 8]);
            lsum[0] = __builtin_amdgcn_mfma_f32_16x16x32_bf16(pf0, ones, lsum[0], 0, 0, 0);
            lsum[1] = __builtin_amdgcn_mfma_f32_16x16x32_bf16(pf1, ones, lsum[1], 0, 0, 0);
            const unsigned short* vp = vbase + ((size_t)(kv0 >> 5) + kc) * 2048;
#pragma unroll
            for (int dt = 0; dt < 4; dt++) {
                bf16x8 vf = *(const bf16x8*)(vp + dt * 512);
                oacc[0][dt] = __builtin_amdgcn_mfma_f32_16x16x32_bf16(pf0, vf, oacc[0][dt], 0, 0, 0);
                oacc[1][dt] = __builtin_amdgcn_mfma_f32_16x16x32_bf16(pf1, vf, oacc[1][dt], 0, 0, 0);
            }
        }
    }

    // epilogue: lsum[qs][r] is l for q = q0+qs*16+g*4+r (same lane as oacc rows)
#pragma unroll
    for (int qs = 0; qs < 2; qs++)
#pragma unroll
        for (int r = 0; r < 4; r++) {
            float rl = 1.f / lsum[qs][r];
            size_t orow = (size_t)(bS + q0 + qs * 16 + g * 4 + r) * 1024 + hcol;
#pragma unroll
            for (int dt = 0; dt < 4; dt++)
                attnb[orow + dt * 16 + fr] = f2bf(oacc[qs][dt][r] * rl);
        }
}

extern "C" void kernel_launch(void* const* d_in, const int* in_sizes, int n_in,
                              void* d_out, int out_size, void* d_ws, size_t ws_size,
                              hipStream_t stream) {
    const float* x      = (const float*)d_in[0]; // [4,2048,1024]
    const float* W_qkv  = (const float*)d_in[1]; // [1024,3072]
    const float* b_qkv  = (const float*)d_in[2]; // [3072]
    const float* W_proj = (const float*)d_in[3]; // [1024,1024]
    const float* b_proj = (const float*)d_in[4]; // [1024]
    float* out = (float*)d_out;                  // [4,2048,1024]

    char* ws = (char*)d_ws;
    // lifetimes: x_bf,WqkvT die after gemm1; KVb dies after pack; Kp aliases x_bf;
    // attnb aliases KVb. Peak = 88 MiB (same footprint as prior rounds).
    unsigned short* x_bf   = (unsigned short*)(ws);                // [0,16M)
    unsigned short* WqkvT  = (unsigned short*)(ws + 16777216);     // [16M,22M)
    unsigned short* Qb     = (unsigned short*)(ws + 23068672);     // [22M,38M)
    unsigned short* KVb    = (unsigned short*)(ws + 39845888);     // [38M,70M)
    unsigned short* Kp     = (unsigned short*)(ws);                // reuses x_bf
    unsigned short* Vp     = (unsigned short*)(ws + 73400320);     // [70M,86M)
    unsigned short* attnb  = (unsigned short*)(ws + 39845888);     // reuses KVb
    unsigned short* WprojT = (unsigned short*)(ws + 90177536);     // [86M,88M)

    // 1) casts / transposes (Q columns of W_qkv pre-scaled into exp2 domain)
    cast_f32_bf16<<<(ROWS * DIM / 4 + 255) / 256, 256, 0, stream>>>(x, x_bf, ROWS * DIM / 4);
    transpose_cast<<<dim3(3 * DIM / 32, DIM / 32), 256, 0, stream>>>(W_qkv, WqkvT, DIM, 3 * DIM, DIM, SCL);
    transpose_cast<<<dim3(DIM / 32, DIM / 32), 256, 0, stream>>>(W_proj, WprojT, DIM, DIM, 0, 1.f);

    // 2) qkv = x @ W_qkv + b_qkv  -> Qb (bf16, scaled) + KVb (bf16)
    gemm_bt_bias<<<dim3(3 * DIM / 128, ROWS / 128), 256, 0, stream>>>(
        x_bf, WqkvT, b_qkv, Qb, KVb, nullptr, ROWS, 3 * DIM, DIM, DIM);

    // 3) pack K,V into fragment-major layouts (x_bf dead; Kp reuses it)
    pack_kv<<<dim3(SEQ / 64, BATCH * NHEADS), 256, 0, stream>>>(KVb, Kp, Vp);

    // 4) attention (KVb dead; attnb reuses it)
    attn_kernel<<<dim3(SEQ / 128, BATCH * NHEADS), 256, 0, stream>>>(Qb, Kp, Vp, attnb);

    // 5) out = attn @ W_proj + b_proj (fp32 out)
    gemm_bt_bias<<<dim3(DIM / 128, ROWS / 128), 256, 0, stream>>>(
        attnb, WprojT, b_proj, nullptr, nullptr, out, ROWS, DIM, DIM, 0);
}

// Round 5
// 323.419 us; speedup vs baseline: 1.0726x; 1.0726x over previous
//
#include <hip/hip_runtime.h>
#include <hip/hip_bf16.h>

typedef __attribute__((ext_vector_type(8))) __bf16 bf16x8;
typedef __attribute__((ext_vector_type(4))) float f32x4;
typedef __attribute__((ext_vector_type(16))) float f32x16;

#define DIM 1024
#define NHEADS 16
#define HDIM 64
#define BATCH 4
#define SEQ 2048
#define ROWS (BATCH * SEQ) /* 8192 */
#define SCL 0.18033688011112042f /* 0.125 * log2(e) */

__device__ inline unsigned short f2bf(float f) {
    __hip_bfloat16 h = __float2bfloat16(f);
    return *reinterpret_cast<unsigned short*>(&h);
}

// pack two floats to bf16x2 (RNE) -- v_cvt_pk_bf16_f32 on gfx950
__device__ inline unsigned int packbf2(float a, float b) {
    unsigned short ua = __builtin_bit_cast(unsigned short, (__bf16)a);
    unsigned short ub = __builtin_bit_cast(unsigned short, (__bf16)b);
    return (unsigned int)ua | ((unsigned int)ub << 16);
}

typedef const __attribute__((address_space(1))) unsigned int* gas_ptr;
typedef __attribute__((address_space(3))) unsigned int* las_ptr;
__device__ inline void gload16(const void* g, void* l) {
    __builtin_amdgcn_global_load_lds((gas_ptr)g, (las_ptr)l, 16, 0, 0);
}

// ---------------- cast fp32 -> bf16 (4 elems/thread) ----------------
__global__ __launch_bounds__(256) void cast_f32_bf16(const float* __restrict__ in,
                                                     unsigned short* __restrict__ out,
                                                     int n4) {
    int i = blockIdx.x * 256 + threadIdx.x;
    if (i < n4) {
        float4 v = ((const float4*)in)[i];
        ushort4 o;
        o.x = f2bf(v.x); o.y = f2bf(v.y); o.z = f2bf(v.z); o.w = f2bf(v.w);
        ((ushort4*)out)[i] = o;
    }
}

// ------------- transpose + cast: in[R][C] fp32 -> out[C][R] bf16 -------------
// rows with orow < srows get scaled by scl (folds softmax scale into W_qkv Q cols)
__global__ __launch_bounds__(256) void transpose_cast(const float* __restrict__ in,
                                                      unsigned short* __restrict__ out,
                                                      int R, int C, int srows, float scl) {
    __shared__ float tile[32][33];
    int c0 = blockIdx.x * 32, r0 = blockIdx.y * 32;
    int tx = threadIdx.x & 31, ty = threadIdx.x >> 5; // 32 x 8
#pragma unroll
    for (int i = 0; i < 32; i += 8) {
        int r = r0 + ty + i, c = c0 + tx;
        tile[ty + i][tx] = in[(size_t)r * C + c];
    }
    __syncthreads();
#pragma unroll
    for (int i = 0; i < 32; i += 8) {
        int orow = c0 + ty + i, oc = r0 + tx;
        float v = tile[tx][ty + i];
        if (orow < srows) v *= scl;
        out[(size_t)orow * R + oc] = f2bf(v);
    }
}

// ---------------- GEMM: C = A * Bt^T + bias ----------------
// BK=64 as two 32-chunks (keeps 64B LDS rows conflict-free + wave-linear DMA).
// bf16 path splits: cols [0,1024) -> Cq, cols [1024,N) -> Ckv. fp32 path: Cf.
__global__ __launch_bounds__(256) void gemm_bt_bias(const unsigned short* __restrict__ A,
                                                    const unsigned short* __restrict__ Bt,
                                                    const float* __restrict__ bias,
                                                    unsigned short* __restrict__ Cq,
                                                    unsigned short* __restrict__ Ckv,
                                                    float* __restrict__ Cf,
                                                    int M, int N, int K, int qcols) {
    __shared__ unsigned short As[2][128 * 32];
    __shared__ unsigned short Bs[2][128 * 32];
    const int tid = threadIdx.x;
    const int lane = tid & 63, wave = tid >> 6;
    const int wm = (wave >> 1) * 64, wn = (wave & 1) * 64;
    const int rowA = blockIdx.y * 128, rowB = blockIdx.x * 128;
    const int fr = lane & 15, fo = (lane >> 4) * 8;

    f32x4 acc[4][4] = {};

    for (int k0 = 0; k0 < K; k0 += 64) {
#pragma unroll
        for (int kc = 0; kc < 2; kc++) {
#pragma unroll
            for (int c = 0; c < 2; c++) {
                int o = c * 4096 + tid * 16; // byte offset in 8KB chunk
                int r = o >> 6, cb = o & 63; // 64 B per row (32 bf16)
                int ldsb = c * 4096 + wave * 1024;
                gload16((const char*)A + ((size_t)(rowA + r) * K + k0 + kc * 32) * 2 + cb,
                        (char*)As[kc] + ldsb);
                gload16((const char*)Bt + ((size_t)(rowB + r) * K + k0 + kc * 32) * 2 + cb,
                        (char*)Bs[kc] + ldsb);
            }
        }
        __syncthreads();
#pragma unroll
        for (int kc = 0; kc < 2; kc++) {
            bf16x8 af[4], bfr[4];
#pragma unroll
            for (int i = 0; i < 4; i++) {
                af[i]  = *(const bf16x8*)(As[kc] + (wm + i * 16 + fr) * 32 + fo);
                bfr[i] = *(const bf16x8*)(Bs[kc] + (wn + i * 16 + fr) * 32 + fo);
            }
#pragma unroll
            for (int mi = 0; mi < 4; mi++)
#pragma unroll
                for (int ni = 0; ni < 4; ni++)
                    acc[mi][ni] = __builtin_amdgcn_mfma_f32_16x16x32_bf16(af[mi], bfr[ni],
                                                                          acc[mi][ni], 0, 0, 0);
        }
        __syncthreads();
    }

    // C/D layout (16x16): col = lane&15, row = (lane>>4)*4 + reg
    const int cn = lane & 15, cm = (lane >> 4) * 4;
    for (int ni = 0; ni < 4; ni++) {
        int gn = rowB + wn + ni * 16 + cn;
        float bv = bias[gn];
        if (gn < qcols) bv *= SCL;
        for (int mi = 0; mi < 4; mi++) {
#pragma unroll
            for (int r = 0; r < 4; r++) {
                int gm = rowA + wm + mi * 16 + cm + r;
                float v = acc[mi][ni][r] + bv;
                if (Cf) Cf[(size_t)gm * N + gn] = v;
                else if (gn < 1024) Cq[(size_t)gm * 1024 + gn] = f2bf(v);
                else Ckv[(size_t)gm * 2048 + (gn - 1024)] = f2bf(v);
            }
        }
    }
}

// -------- pack K,V into 32x32x16-fragment-major layouts --------
// Kp[bh][S/32][ks=4][lane=64][8]  A-frag: A[m=key(lane&31)][k=ks*16+(lane>>5)*8+j]
// Vp[bh][S/16][dt=2][lane=64][8]  B-frag: B[k=key(lane>>5)*8+j][n=d dt*32+(lane&31)]
__global__ __launch_bounds__(256) void pack_kv(const unsigned short* __restrict__ KVb, // [8192][2048]
                                               unsigned short* __restrict__ Kp,
                                               unsigned short* __restrict__ Vp) {
    __shared__ unsigned short Kt[64][72];
    __shared__ unsigned short Vt[64][68];
    const int tid = threadIdx.x;
    const int s0 = blockIdx.x * 64;
    const int by = blockIdx.y;
    const int b = by >> 4, h = by & 15;
    const size_t rowbase = ((size_t)(b * SEQ + s0)) * 2048 + h * 64;
    const int c = (tid & 7) * 8, rr = tid >> 3; // 8 x 32
#pragma unroll
    for (int p = 0; p < 2; p++) {
        int row = p * 32 + rr;
        const unsigned short* src = KVb + rowbase + (size_t)row * 2048;
        uint4 kv = *(const uint4*)(src + c);
        uint4 vv = *(const uint4*)(src + 1024 + c);
        *(uint2*)&Kt[row][c]     = make_uint2(kv.x, kv.y);
        *(uint2*)&Kt[row][c + 4] = make_uint2(kv.z, kv.w);
        *(uint2*)&Vt[row][c]     = make_uint2(vv.x, vv.y);
        *(uint2*)&Vt[row][c + 4] = make_uint2(vv.z, vv.w);
    }
    __syncthreads();
    // K: 8 frags per 64-key block (ktl[2] x ks[4]) x 64 lanes = 512 x 16B
#pragma unroll
    for (int half = 0; half < 2; half++) {
        int f = half * 256 + tid;
        int ktl = f >> 8, ks = (f >> 6) & 3, ln = f & 63;
        int mm = ln & 31, hh = ln >> 5;
        uint4 d = *(const uint4*)&Kt[ktl * 32 + mm][ks * 16 + hh * 8];
        *(uint4*)(Kp + (((size_t)by * 64 + (s0 >> 5) + ktl) * 4 + ks) * 512 + ln * 8) = d;
    }
    // V: 8 frags per 64-key block (ksl[4] x dt[2])
#pragma unroll
    for (int half = 0; half < 2; half++) {
        int f = half * 256 + tid;
        int ksl = f >> 7, dt = (f >> 6) & 1, ln = f & 63;
        int mm = ln & 31, hh = ln >> 5;
        unsigned short tmp[8];
#pragma unroll
        for (int j = 0; j < 8; j++) tmp[j] = Vt[ksl * 16 + hh * 8 + j][dt * 32 + mm];
        *(uint4*)(Vp + (((size_t)by * 128 + (s0 >> 4) + ksl) * 2 + dt) * 512 + ln * 8) =
            *(uint4*)tmp;
    }
}

// ---------------- flash attention v5: 32x32x16 MFMA, 64 q/wave ----------------
// S^T = K Q^T; C-layout col = q -> per-lane psum for l (one shfl at end).
// K/V fragment-major from L2; P via per-wave swizzled LDS (conflict-free).
__global__ __launch_bounds__(256) void attn_kernel(const unsigned short* __restrict__ Qb, // [8192][1024] prescaled
                                                   const unsigned short* __restrict__ Kp,
                                                   const unsigned short* __restrict__ Vp,
                                                   unsigned short* __restrict__ attnb) { // [8192][1024]
    __shared__ unsigned short Ps[4][2][32 * 128]; // [wave][qt][q][key], 16B-unit swizzle
    const int tid = threadIdx.x;
    const int lane = tid & 63, wave = tid >> 6;
    const int m31 = lane & 31, h = lane >> 5;
    const int by = blockIdx.y;
    const int b = by >> 4;
    const int bS = b * SEQ, hcol = (by & 15) * HDIM;
    const int q0 = blockIdx.x * 256 + wave * 64;

    // Q B-frags: qf[qt][ks]: B[k=ks*16+h*8+j][n=q0+qt*32+m31]
    bf16x8 qf[2][4];
#pragma unroll
    for (int qt = 0; qt < 2; qt++)
#pragma unroll
        for (int ks = 0; ks < 4; ks++)
            qf[qt][ks] = *(const bf16x8*)(Qb + (size_t)(bS + q0 + qt * 32 + m31) * 1024 +
                                          hcol + ks * 16 + h * 8);

    f32x16 oacc[2][2] = {}; // [qt][dt]: C row=q (reg/lane), col=d=dt*32+m31
    float psum[2] = {0.f, 0.f};

    const unsigned short* kbase = Kp + (size_t)by * 64 * 2048 + lane * 8;
    const unsigned short* vbase = Vp + (size_t)by * 128 * 1024 + lane * 8;
    char* Pw0 = (char*)&Ps[wave][0][0];
    char* Pw1 = (char*)&Ps[wave][1][0];

    for (int kv0 = 0; kv0 < SEQ; kv0 += 128) {
        // --- S^T = K Q^T (exp2 domain), exp, pack P ---
#pragma unroll
        for (int kt = 0; kt < 4; kt++) { // 32-key tiles
            const unsigned short* kp = kbase + ((size_t)(kv0 >> 5) + kt) * 2048;
            bf16x8 kf[4];
#pragma unroll
            for (int ks = 0; ks < 4; ks++) kf[ks] = *(const bf16x8*)(kp + ks * 512);
#pragma unroll
            for (int qt = 0; qt < 2; qt++) {
                f32x16 cfrag = {};
#pragma unroll
                for (int ks = 0; ks < 4; ks++)
                    cfrag = __builtin_amdgcn_mfma_f32_32x32x16_bf16(kf[ks], qf[qt][ks],
                                                                    cfrag, 0, 0, 0);
                char* Pw = qt ? Pw1 : Pw0;
                float ls = 0.f;
#pragma unroll
                for (int g2 = 0; g2 < 4; g2++) {
                    float e0 = __builtin_amdgcn_exp2f(cfrag[4 * g2 + 0]);
                    float e1 = __builtin_amdgcn_exp2f(cfrag[4 * g2 + 1]);
                    float e2 = __builtin_amdgcn_exp2f(cfrag[4 * g2 + 2]);
                    float e3 = __builtin_amdgcn_exp2f(cfrag[4 * g2 + 3]);
                    ls += (e0 + e1) + (e2 + e3);
                    uint2 pk;
                    pk.x = packbf2(e0, e1);
                    pk.y = packbf2(e2, e3);
                    int u = (kt * 4 + g2) ^ (m31 & 15); // 16B-unit swizzle
                    *(uint2*)(Pw + m31 * 256 + u * 16 + h * 8) = pk;
                }
                psum[qt] += ls;
            }
        }
        asm volatile("s_waitcnt lgkmcnt(0)" ::: "memory"); // P stores -> same-wave reads

        // --- O += P V ---
#pragma unroll
        for (int ks16 = 0; ks16 < 8; ks16++) {
            const unsigned short* vp = vbase + ((size_t)(kv0 >> 4) + ks16) * 1024;
            bf16x8 vf0 = *(const bf16x8*)(vp);
            bf16x8 vf1 = *(const bf16x8*)(vp + 512);
            int u = (ks16 * 2 + h) ^ (m31 & 15);
            bf16x8 pf0 = *(const bf16x8*)(Pw0 + m31 * 256 + u * 16);
            bf16x8 pf1 = *(const bf16x8*)(Pw1 + m31 * 256 + u * 16);
            oacc[0][0] = __builtin_amdgcn_mfma_f32_32x32x16_bf16(pf0, vf0, oacc[0][0], 0, 0, 0);
            oacc[0][1] = __builtin_amdgcn_mfma_f32_32x32x16_bf16(pf0, vf1, oacc[0][1], 0, 0, 0);
            oacc[1][0] = __builtin_amdgcn_mfma_f32_32x32x16_bf16(pf1, vf0, oacc[1][0], 0, 0, 0);
            oacc[1][1] = __builtin_amdgcn_mfma_f32_32x32x16_bf16(pf1, vf1, oacc[1][1], 0, 0, 0);
        }
    }

    // epilogue: l[q] = psum(h=0) + psum(h=1); C rows: row=(r&3)+8*(r>>2)+4h
#pragma unroll
    for (int qt = 0; qt < 2; qt++) {
        float lt = psum[qt] + __shfl_xor(psum[qt], 32, 64);
        float rl = 1.f / lt; // valid on lanes where m31 == q
#pragma unroll
        for (int r = 0; r < 16; r++) {
            int row = (r & 3) + 8 * (r >> 2) + 4 * h;
            float rlr = __shfl(rl, row, 64);
            size_t orow = (size_t)(bS + q0 + qt * 32 + row) * 1024 + hcol;
            attnb[orow + m31]      = f2bf(oacc[qt][0][r] * rlr);
            attnb[orow + 32 + m31] = f2bf(oacc[qt][1][r] * rlr);
        }
    }
}

extern "C" void kernel_launch(void* const* d_in, const int* in_sizes, int n_in,
                              void* d_out, int out_size, void* d_ws, size_t ws_size,
                              hipStream_t stream) {
    const float* x      = (const float*)d_in[0]; // [4,2048,1024]
    const float* W_qkv  = (const float*)d_in[1]; // [1024,3072]
    const float* b_qkv  = (const float*)d_in[2]; // [3072]
    const float* W_proj = (const float*)d_in[3]; // [1024,1024]
    const float* b_proj = (const float*)d_in[4]; // [1024]
    float* out = (float*)d_out;                  // [4,2048,1024]

    char* ws = (char*)d_ws;
    // lifetimes: x_bf,WqkvT die after gemm1; KVb dies after pack; Kp aliases x_bf;
    // attnb aliases KVb. Peak 88 MiB (same as prior rounds).
    unsigned short* x_bf   = (unsigned short*)(ws);                // [0,16M)
    unsigned short* WqkvT  = (unsigned short*)(ws + 16777216);     // [16M,22M)
    unsigned short* Qb     = (unsigned short*)(ws + 23068672);     // [22M,38M)
    unsigned short* KVb    = (unsigned short*)(ws + 39845888);     // [38M,70M)
    unsigned short* Kp     = (unsigned short*)(ws);                // reuses x_bf
    unsigned short* Vp     = (unsigned short*)(ws + 73400320);     // [70M,86M)
    unsigned short* attnb  = (unsigned short*)(ws + 39845888);     // reuses KVb
    unsigned short* WprojT = (unsigned short*)(ws + 90177536);     // [86M,88M)

    // 1) casts / transposes (Q columns of W_qkv pre-scaled into exp2 domain)
    cast_f32_bf16<<<(ROWS * DIM / 4 + 255) / 256, 256, 0, stream>>>(x, x_bf, ROWS * DIM / 4);
    transpose_cast<<<dim3(3 * DIM / 32, DIM / 32), 256, 0, stream>>>(W_qkv, WqkvT, DIM, 3 * DIM, DIM, SCL);
    transpose_cast<<<dim3(DIM / 32, DIM / 32), 256, 0, stream>>>(W_proj, WprojT, DIM, DIM, 0, 1.f);

    // 2) qkv = x @ W_qkv + b_qkv  -> Qb (bf16, scaled) + KVb (bf16)
    gemm_bt_bias<<<dim3(3 * DIM / 128, ROWS / 128), 256, 0, stream>>>(
        x_bf, WqkvT, b_qkv, Qb, KVb, nullptr, ROWS, 3 * DIM, DIM, DIM);

    // 3) pack K,V into fragment-major layouts (x_bf dead; Kp reuses it)
    pack_kv<<<dim3(SEQ / 64, BATCH * NHEADS), 256, 0, stream>>>(KVb, Kp, Vp);

    // 4) attention (KVb dead; attnb reuses it): 256 q/block
    attn_kernel<<<dim3(SEQ / 256, BATCH * NHEADS), 256, 0, stream>>>(Qb, Kp, Vp, attnb);

    // 5) out = attn @ W_proj + b_proj (fp32 out)
    gemm_bt_bias<<<dim3(DIM / 128, ROWS / 128), 256, 0, stream>>>(
        attnb, WprojT, b_proj, nullptr, nullptr, out, ROWS, DIM, DIM, 0);
}

// Round 6
// 298.464 us; speedup vs baseline: 1.1623x; 1.0836x over previous
//
#include <hip/hip_runtime.h>
#include <hip/hip_bf16.h>

typedef __attribute__((ext_vector_type(8))) __bf16 bf16x8;
typedef __attribute__((ext_vector_type(4))) float f32x4;
typedef __attribute__((ext_vector_type(16))) float f32x16;
typedef __attribute__((ext_vector_type(4))) unsigned int u32x4;

#define DIM 1024
#define NHEADS 16
#define HDIM 64
#define BATCH 4
#define SEQ 2048
#define ROWS (BATCH * SEQ) /* 8192 */
#define SCL 0.18033688011112042f /* 0.125 * log2(e) */

__device__ inline unsigned short f2bf(float f) {
    __hip_bfloat16 h = __float2bfloat16(f);
    return *reinterpret_cast<unsigned short*>(&h);
}

// pack two floats to bf16x2 (RNE) -- v_cvt_pk_bf16_f32 on gfx950
__device__ inline unsigned int packbf2(float a, float b) {
    unsigned short ua = __builtin_bit_cast(unsigned short, (__bf16)a);
    unsigned short ub = __builtin_bit_cast(unsigned short, (__bf16)b);
    return (unsigned int)ua | ((unsigned int)ub << 16);
}

typedef const __attribute__((address_space(1))) unsigned int* gas_ptr;
typedef __attribute__((address_space(3))) unsigned int* las_ptr;
__device__ inline void gload16(const void* g, void* l) {
    __builtin_amdgcn_global_load_lds((gas_ptr)g, (las_ptr)l, 16, 0, 0);
}

// ---------------- cast fp32 -> bf16 (4 elems/thread) ----------------
__global__ __launch_bounds__(256) void cast_f32_bf16(const float* __restrict__ in,
                                                     unsigned short* __restrict__ out,
                                                     int n4) {
    int i = blockIdx.x * 256 + threadIdx.x;
    if (i < n4) {
        float4 v = ((const float4*)in)[i];
        ushort4 o;
        o.x = f2bf(v.x); o.y = f2bf(v.y); o.z = f2bf(v.z); o.w = f2bf(v.w);
        ((ushort4*)out)[i] = o;
    }
}

// ------------- transpose + cast: in[R][C] fp32 -> out[C][R] bf16 -------------
// rows with orow < srows get scaled by scl (folds softmax scale into W_qkv Q cols)
__global__ __launch_bounds__(256) void transpose_cast(const float* __restrict__ in,
                                                      unsigned short* __restrict__ out,
                                                      int R, int C, int srows, float scl) {
    __shared__ float tile[32][33];
    int c0 = blockIdx.x * 32, r0 = blockIdx.y * 32;
    int tx = threadIdx.x & 31, ty = threadIdx.x >> 5; // 32 x 8
#pragma unroll
    for (int i = 0; i < 32; i += 8) {
        int r = r0 + ty + i, c = c0 + tx;
        tile[ty + i][tx] = in[(size_t)r * C + c];
    }
    __syncthreads();
#pragma unroll
    for (int i = 0; i < 32; i += 8) {
        int orow = c0 + ty + i, oc = r0 + tx;
        float v = tile[tx][ty + i];
        if (orow < srows) v *= scl;
        out[(size_t)orow * R + oc] = f2bf(v);
    }
}

// ---------------- GEMM: C = A * Bt^T + bias ----------------
// BK=64 as two 32-chunks (keeps 64B LDS rows conflict-free + wave-linear DMA).
// bf16 path splits: cols [0,1024) -> Cq, cols [1024,N) -> Ckv. fp32 path: Cf.
__global__ __launch_bounds__(256) void gemm_bt_bias(const unsigned short* __restrict__ A,
                                                    const unsigned short* __restrict__ Bt,
                                                    const float* __restrict__ bias,
                                                    unsigned short* __restrict__ Cq,
                                                    unsigned short* __restrict__ Ckv,
                                                    float* __restrict__ Cf,
                                                    int M, int N, int K, int qcols) {
    __shared__ unsigned short As[2][128 * 32];
    __shared__ unsigned short Bs[2][128 * 32];
    const int tid = threadIdx.x;
    const int lane = tid & 63, wave = tid >> 6;
    const int wm = (wave >> 1) * 64, wn = (wave & 1) * 64;
    const int rowA = blockIdx.y * 128, rowB = blockIdx.x * 128;
    const int fr = lane & 15, fo = (lane >> 4) * 8;

    f32x4 acc[4][4] = {};

    for (int k0 = 0; k0 < K; k0 += 64) {
#pragma unroll
        for (int kc = 0; kc < 2; kc++) {
#pragma unroll
            for (int c = 0; c < 2; c++) {
                int o = c * 4096 + tid * 16; // byte offset in 8KB chunk
                int r = o >> 6, cb = o & 63; // 64 B per row (32 bf16)
                int ldsb = c * 4096 + wave * 1024;
                gload16((const char*)A + ((size_t)(rowA + r) * K + k0 + kc * 32) * 2 + cb,
                        (char*)As[kc] + ldsb);
                gload16((const char*)Bt + ((size_t)(rowB + r) * K + k0 + kc * 32) * 2 + cb,
                        (char*)Bs[kc] + ldsb);
            }
        }
        __syncthreads();
#pragma unroll
        for (int kc = 0; kc < 2; kc++) {
            bf16x8 af[4], bfr[4];
#pragma unroll
            for (int i = 0; i < 4; i++) {
                af[i]  = *(const bf16x8*)(As[kc] + (wm + i * 16 + fr) * 32 + fo);
                bfr[i] = *(const bf16x8*)(Bs[kc] + (wn + i * 16 + fr) * 32 + fo);
            }
#pragma unroll
            for (int mi = 0; mi < 4; mi++)
#pragma unroll
                for (int ni = 0; ni < 4; ni++)
                    acc[mi][ni] = __builtin_amdgcn_mfma_f32_16x16x32_bf16(af[mi], bfr[ni],
                                                                          acc[mi][ni], 0, 0, 0);
        }
        __syncthreads();
    }

    // C/D layout (16x16): col = lane&15, row = (lane>>4)*4 + reg
    const int cn = lane & 15, cm = (lane >> 4) * 4;
    for (int ni = 0; ni < 4; ni++) {
        int gn = rowB + wn + ni * 16 + cn;
        float bv = bias[gn];
        if (gn < qcols) bv *= SCL;
        for (int mi = 0; mi < 4; mi++) {
#pragma unroll
            for (int r = 0; r < 4; r++) {
                int gm = rowA + wm + mi * 16 + cm + r;
                float v = acc[mi][ni][r] + bv;
                if (Cf) Cf[(size_t)gm * N + gn] = v;
                else if (gn < 1024) Cq[(size_t)gm * 1024 + gn] = f2bf(v);
                else Ckv[(size_t)gm * 2048 + (gn - 1024)] = f2bf(v);
            }
        }
    }
}

// -------- pack K,V into 32x32x16-fragment-major layouts --------
// Kp[bh][S/32][ks=4][lane=64][8]  A-frag: A[m=key(lane&31)][k=ks*16+(lane>>5)*8+j]
// Vp[bh][S/16][dt=2][lane=64][8]  B-frag with the S^T C-layout key permutation
//   baked in: B[k_virt=hh*8+j] maps to key (j&3)+8*(j>>2)+4*hh within the 16-key
//   group, so exp(S^T C-frag) registers ARE the PV A-frag (no LDS round-trip).
__global__ __launch_bounds__(256) void pack_kv(const unsigned short* __restrict__ KVb, // [8192][2048]
                                               unsigned short* __restrict__ Kp,
                                               unsigned short* __restrict__ Vp) {
    __shared__ unsigned short Kt[64][72];
    __shared__ unsigned short Vt[64][68];
    const int tid = threadIdx.x;
    const int s0 = blockIdx.x * 64;
    const int by = blockIdx.y;
    const int b = by >> 4, h = by & 15;
    const size_t rowbase = ((size_t)(b * SEQ + s0)) * 2048 + h * 64;
    const int c = (tid & 7) * 8, rr = tid >> 3; // 8 x 32
#pragma unroll
    for (int p = 0; p < 2; p++) {
        int row = p * 32 + rr;
        const unsigned short* src = KVb + rowbase + (size_t)row * 2048;
        uint4 kv = *(const uint4*)(src + c);
        uint4 vv = *(const uint4*)(src + 1024 + c);
        *(uint2*)&Kt[row][c]     = make_uint2(kv.x, kv.y);
        *(uint2*)&Kt[row][c + 4] = make_uint2(kv.z, kv.w);
        *(uint2*)&Vt[row][c]     = make_uint2(vv.x, vv.y);
        *(uint2*)&Vt[row][c + 4] = make_uint2(vv.z, vv.w);
    }
    __syncthreads();
    // K: 8 frags per 64-key block (ktl[2] x ks[4]) x 64 lanes = 512 x 16B
#pragma unroll
    for (int half = 0; half < 2; half++) {
        int f = half * 256 + tid;
        int ktl = f >> 8, ks = (f >> 6) & 3, ln = f & 63;
        int mm = ln & 31, hh = ln >> 5;
        uint4 d = *(const uint4*)&Kt[ktl * 32 + mm][ks * 16 + hh * 8];
        *(uint4*)(Kp + (((size_t)by * 64 + (s0 >> 5) + ktl) * 4 + ks) * 512 + ln * 8) = d;
    }
    // V: 8 frags per 64-key block (ksl[4] x dt[2]), permuted key order
#pragma unroll
    for (int half = 0; half < 2; half++) {
        int f = half * 256 + tid;
        int ksl = f >> 7, dt = (f >> 6) & 1, ln = f & 63;
        int mm = ln & 31, hh = ln >> 5;
        unsigned short tmp[8];
#pragma unroll
        for (int j = 0; j < 8; j++)
            tmp[j] = Vt[ksl * 16 + (j & 3) + 8 * (j >> 2) + 4 * hh][dt * 32 + mm];
        *(uint4*)(Vp + (((size_t)by * 128 + (s0 >> 4) + ksl) * 2 + dt) * 512 + ln * 8) =
            *(uint4*)tmp;
    }
}

// ---------------- flash attention v6: zero-LDS, zero-barrier ----------------
// S^T = K Q^T (32x32x16); exp2 of the C-frag, packed in register, IS the PV
// A-frag because V was packed with the matching key permutation. 64 q/wave.
__global__ __launch_bounds__(256, 2) void attn_kernel(const unsigned short* __restrict__ Qb, // [8192][1024] prescaled
                                                      const unsigned short* __restrict__ Kp,
                                                      const unsigned short* __restrict__ Vp,
                                                      unsigned short* __restrict__ attnb) { // [8192][1024]
    const int tid = threadIdx.x;
    const int lane = tid & 63, wave = tid >> 6;
    const int m31 = lane & 31, h = lane >> 5;
    const int by = blockIdx.y;
    const int b = by >> 4;
    const int bS = b * SEQ, hcol = (by & 15) * HDIM;
    const int q0 = blockIdx.x * 256 + wave * 64;

    // Q B-frags: qf[qt][ks]: B[k=ks*16+h*8+j][n=q0+qt*32+m31]
    bf16x8 qf[2][4];
#pragma unroll
    for (int qt = 0; qt < 2; qt++)
#pragma unroll
        for (int ks = 0; ks < 4; ks++)
            qf[qt][ks] = *(const bf16x8*)(Qb + (size_t)(bS + q0 + qt * 32 + m31) * 1024 +
                                          hcol + ks * 16 + h * 8);

    f32x16 oacc[2][2] = {}; // [qt][dt]: C row=q, col=d=dt*32+m31
    float psum[2] = {0.f, 0.f};

    const unsigned short* kbase = Kp + (size_t)by * 64 * 2048 + lane * 8;
    const unsigned short* vbase = Vp + (size_t)by * 128 * 1024 + lane * 8;

#pragma unroll 2
    for (int ku = 0; ku < SEQ / 32; ku++) { // 32-key units
        const unsigned short* kp = kbase + (size_t)ku * 2048;
        bf16x8 kf[4];
#pragma unroll
        for (int ks = 0; ks < 4; ks++) kf[ks] = *(const bf16x8*)(kp + ks * 512);
        bf16x8 vf[2][2];
#pragma unroll
        for (int ks = 0; ks < 2; ks++) {
            const unsigned short* vp = vbase + ((size_t)ku * 2 + ks) * 1024;
            vf[ks][0] = *(const bf16x8*)(vp);
            vf[ks][1] = *(const bf16x8*)(vp + 512);
        }
#pragma unroll
        for (int qt = 0; qt < 2; qt++) {
            f32x16 cfrag = {};
#pragma unroll
            for (int ks = 0; ks < 4; ks++)
                cfrag = __builtin_amdgcn_mfma_f32_32x32x16_bf16(kf[ks], qf[qt][ks],
                                                                cfrag, 0, 0, 0);
            // exp2 + pack; packed regs = PV A-frag (keys permuted to match Vp)
            unsigned int pk[8];
            float ls = 0.f;
#pragma unroll
            for (int p = 0; p < 8; p++) {
                float e0 = __builtin_amdgcn_exp2f(cfrag[2 * p]);
                float e1 = __builtin_amdgcn_exp2f(cfrag[2 * p + 1]);
                ls += e0 + e1;
                pk[p] = packbf2(e0, e1);
            }
            psum[qt] += ls;
            u32x4 lo = {pk[0], pk[1], pk[2], pk[3]};
            u32x4 hi = {pk[4], pk[5], pk[6], pk[7]};
            bf16x8 pa0 = __builtin_bit_cast(bf16x8, lo); // keys [ku*32, +16) permuted
            bf16x8 pa1 = __builtin_bit_cast(bf16x8, hi); // keys [ku*32+16, +16)
            oacc[qt][0] = __builtin_amdgcn_mfma_f32_32x32x16_bf16(pa0, vf[0][0], oacc[qt][0], 0, 0, 0);
            oacc[qt][1] = __builtin_amdgcn_mfma_f32_32x32x16_bf16(pa0, vf[0][1], oacc[qt][1], 0, 0, 0);
            oacc[qt][0] = __builtin_amdgcn_mfma_f32_32x32x16_bf16(pa1, vf[1][0], oacc[qt][0], 0, 0, 0);
            oacc[qt][1] = __builtin_amdgcn_mfma_f32_32x32x16_bf16(pa1, vf[1][1], oacc[qt][1], 0, 0, 0);
        }
    }

    // epilogue: l[q] = psum(h=0) + psum(h=1); C rows: row=(r&3)+8*(r>>2)+4h
#pragma unroll
    for (int qt = 0; qt < 2; qt++) {
        float lt = psum[qt] + __shfl_xor(psum[qt], 32, 64);
        float rl = 1.f / lt; // valid on lanes where m31 == q
#pragma unroll
        for (int r = 0; r < 16; r++) {
            int row = (r & 3) + 8 * (r >> 2) + 4 * h;
            float rlr = __shfl(rl, row, 64);
            size_t orow = (size_t)(bS + q0 + qt * 32 + row) * 1024 + hcol;
            attnb[orow + m31]      = f2bf(oacc[qt][0][r] * rlr);
            attnb[orow + 32 + m31] = f2bf(oacc[qt][1][r] * rlr);
        }
    }
}

extern "C" void kernel_launch(void* const* d_in, const int* in_sizes, int n_in,
                              void* d_out, int out_size, void* d_ws, size_t ws_size,
                              hipStream_t stream) {
    const float* x      = (const float*)d_in[0]; // [4,2048,1024]
    const float* W_qkv  = (const float*)d_in[1]; // [1024,3072]
    const float* b_qkv  = (const float*)d_in[2]; // [3072]
    const float* W_proj = (const float*)d_in[3]; // [1024,1024]
    const float* b_proj = (const float*)d_in[4]; // [1024]
    float* out = (float*)d_out;                  // [4,2048,1024]

    char* ws = (char*)d_ws;
    // lifetimes: x_bf,WqkvT die after gemm1; KVb dies after pack; Kp aliases x_bf;
    // attnb aliases KVb. Peak 88 MiB.
    unsigned short* x_bf   = (unsigned short*)(ws);                // [0,16M)
    unsigned short* WqkvT  = (unsigned short*)(ws + 16777216);     // [16M,22M)
    unsigned short* Qb     = (unsigned short*)(ws + 23068672);     // [22M,38M)
    unsigned short* KVb    = (unsigned short*)(ws + 39845888);     // [38M,70M)
    unsigned short* Kp     = (unsigned short*)(ws);                // reuses x_bf
    unsigned short* Vp     = (unsigned short*)(ws + 73400320);     // [70M,86M)
    unsigned short* attnb  = (unsigned short*)(ws + 39845888);     // reuses KVb
    unsigned short* WprojT = (unsigned short*)(ws + 90177536);     // [86M,88M)

    // 1) casts / transposes (Q columns of W_qkv pre-scaled into exp2 domain)
    cast_f32_bf16<<<(ROWS * DIM / 4 + 255) / 256, 256, 0, stream>>>(x, x_bf, ROWS * DIM / 4);
    transpose_cast<<<dim3(3 * DIM / 32, DIM / 32), 256, 0, stream>>>(W_qkv, WqkvT, DIM, 3 * DIM, DIM, SCL);
    transpose_cast<<<dim3(DIM / 32, DIM / 32), 256, 0, stream>>>(W_proj, WprojT, DIM, DIM, 0, 1.f);

    // 2) qkv = x @ W_qkv + b_qkv  -> Qb (bf16, scaled) + KVb (bf16)
    gemm_bt_bias<<<dim3(3 * DIM / 128, ROWS / 128), 256, 0, stream>>>(
        x_bf, WqkvT, b_qkv, Qb, KVb, nullptr, ROWS, 3 * DIM, DIM, DIM);

    // 3) pack K,V into fragment-major layouts (x_bf dead; Kp reuses it)
    pack_kv<<<dim3(SEQ / 64, BATCH * NHEADS), 256, 0, stream>>>(KVb, Kp, Vp);

    // 4) attention (KVb dead; attnb reuses it): 256 q/block
    attn_kernel<<<dim3(SEQ / 256, BATCH * NHEADS), 256, 0, stream>>>(Qb, Kp, Vp, attnb);

    // 5) out = attn @ W_proj + b_proj (fp32 out)
    gemm_bt_bias<<<dim3(DIM / 128, ROWS / 128), 256, 0, stream>>>(
        attnb, WprojT, b_proj, nullptr, nullptr, out, ROWS, DIM, DIM, 0);
}